// Round 8
// baseline (65.233 us; speedup 1.0000x reference)
//
#include <hip/hip_runtime.h>
#include <math.h>

#define NBOX 2048
#define NBATCH 8
#define MAX_INST 100
#define MIN_CONF 0.15f
#define NMS_THR 0.3f
#define SBLOCK 512
#define NBLOCK 1024

typedef unsigned long long ull;

// Decode one box exactly in the reference's f32 op order (no FMA contraction).
__device__ inline float4 decode_box(float4 r, float4 d,
                                    float wy1, float wx1, float wy2, float wx2) {
    float h  = __fsub_rn(r.z, r.x);
    float w  = __fsub_rn(r.w, r.y);
    float dy = __fmul_rn(d.x, 0.1f);
    float dx = __fmul_rn(d.y, 0.1f);
    float dh = __fmul_rn(d.z, 0.2f);
    float dw = __fmul_rn(d.w, 0.2f);
    float cy = __fadd_rn(__fadd_rn(r.x, __fmul_rn(0.5f, h)), __fmul_rn(dy, h));
    float cx = __fadd_rn(__fadd_rn(r.y, __fmul_rn(0.5f, w)), __fmul_rn(dx, w));
    float h2 = __fmul_rn(h, expf(dh));
    float w2 = __fmul_rn(w, expf(dw));
    float y1 = __fsub_rn(cy, __fmul_rn(0.5f, h2));
    float x1 = __fsub_rn(cx, __fmul_rn(0.5f, w2));
    float y2 = __fadd_rn(y1, h2);
    float x2 = __fadd_rn(x1, w2);
    float4 b;
    b.x = fminf(fmaxf(y1, wy1), wy2);
    b.y = fminf(fmaxf(x1, wx1), wx2);
    b.z = fminf(fmaxf(y2, wy1), wy2);
    b.w = fminf(fmaxf(x2, wx1), wx2);
    return b;
}

// Exact reference op order (operand-symmetric => iou(a,b)==iou(b,a)).
__device__ inline float iou_pair(float4 a, float4 b) {
    float areaA = __fmul_rn(__fsub_rn(a.z, a.x), __fsub_rn(a.w, a.y));
    float areaB = __fmul_rn(__fsub_rn(b.z, b.x), __fsub_rn(b.w, b.y));
    float iy1 = fmaxf(a.x, b.x);
    float ix1 = fmaxf(a.y, b.y);
    float iy2 = fminf(a.z, b.z);
    float ix2 = fminf(a.w, b.w);
    float ih = fmaxf(__fsub_rn(iy2, iy1), 0.0f);
    float iw = fmaxf(__fsub_rn(ix2, ix1), 0.0f);
    float inter = __fmul_rn(ih, iw);
    float uni = __fadd_rn(__fsub_rn(__fadd_rn(areaA, areaB), inter), 1e-8f);
    return __fdiv_rn(inter, uni);
}

__device__ inline ull shfl_xor64(ull x, int d) {
    unsigned lo = (unsigned)x, hi = (unsigned)(x >> 32);
    lo = __shfl_xor(lo, d);
    hi = __shfl_xor(hi, d);
    return ((ull)hi << 32) | lo;
}

__device__ inline void cmpsel(ull& a, ull& b, bool takeMinA) {
    ull mn = a < b ? a : b;
    ull mx = a < b ? b : a;
    a = takeMinA ? mn : mx;
    b = takeMinA ? mx : mn;
}

// ---- K1: parallel decode (one thread per box) ----
__global__ __launch_bounds__(256)
void k_decode(const float* __restrict__ rois,
              const float* __restrict__ deltas,
              const float* __restrict__ window,
              float4* __restrict__ wsbox) {
    int g = blockIdx.x * 256 + threadIdx.x;    // grid sized exactly NBATCH*NBOX
    int b = g >> 11;
    float4 r = ((const float4*)rois)[g];
    float4 d = ((const float4*)deltas)[g];
    wsbox[g] = decode_box(r, d, window[b * 4 + 0], window[b * 4 + 1],
                          window[b * 4 + 2], window[b * 4 + 3]);
}

// ---- K2: per-batch register bitonic sort of (score,idx) keys ----
__global__ __launch_bounds__(SBLOCK)
void k_sort(const float* __restrict__ scores_in, ull* __restrict__ wskeys) {
    __shared__ ull keys[NBOX];
    const int b = blockIdx.x, tid = threadIdx.x;
    const int e0 = tid * 4;
    ull v[4];
    {
        float4 sc = ((const float4*)(scores_in + (size_t)b * NBOX))[tid];
        float s4[4] = {sc.x, sc.y, sc.z, sc.w};
#pragma unroll
        for (int s = 0; s < 4; ++s) {
            unsigned u = __float_as_uint(s4[s]);
            u = (u & 0x80000000u) ? ~u : (u | 0x80000000u);
            v[s] = ((ull)(~u) << 32) | (unsigned)(e0 + s);
        }
    }
    for (unsigned k = 2; k <= NBOX; k <<= 1) {
        if (k >= 512) {
#pragma unroll
            for (int s = 0; s < 4; ++s) keys[e0 + s] = v[s];
            __syncthreads();
            for (unsigned j = k >> 1; j >= 256; j >>= 1) {
                for (int t = tid; t < NBOX / 2; t += SBLOCK) {
                    int i = 2 * t - (t & (j - 1));
                    int p = i | j;
                    bool up = ((i & k) == 0);
                    ull a = keys[i], c = keys[p];
                    bool sw = up ? (a > c) : (a < c);
                    if (sw) { keys[i] = c; keys[p] = a; }
                }
                __syncthreads();
            }
#pragma unroll
            for (int s = 0; s < 4; ++s) v[s] = keys[e0 + s];
        }
        unsigned jstart = ((k >> 1) > 128u) ? 128u : (k >> 1);
        for (unsigned j = jstart; j >= 4; j >>= 1) {
            int d = (int)(j >> 2);
#pragma unroll
            for (int s = 0; s < 4; ++s) {
                ull p = shfl_xor64(v[s], d);
                int e = e0 + s;
                bool takeMin = (((e & j) == 0) == ((e & k) == 0));
                v[s] = takeMin ? (v[s] < p ? v[s] : p) : (v[s] > p ? v[s] : p);
            }
        }
        if (k >= 4) {
            bool up = ((e0 & k) == 0);
            cmpsel(v[0], v[2], up);
            cmpsel(v[1], v[3], up);
        }
        {
            bool upA = ((e0 & k) == 0);
            bool upB = (((e0 + 2) & k) == 0);
            cmpsel(v[0], v[1], upA);
            cmpsel(v[2], v[3], upB);
        }
    }
    ulonglong2* wk = (ulonglong2*)(wskeys + (size_t)b * NBOX);
    ulonglong2 w0; w0.x = v[0]; w0.y = v[1];
    ulonglong2 w1; w1.x = v[2]; w1.y = v[3];
    wk[tid * 2]     = w0;
    wk[tid * 2 + 1] = w1;
}

// ---- K3: staged NMS, 128-wide windows, prefetch, 16-wave dead-check ----
__global__ __launch_bounds__(NBLOCK)
void k_nms(const float4* __restrict__ wsbox,
           const ull* __restrict__ wskeys,
           const float* __restrict__ scores_in,
           float* __restrict__ out) {
    const int b = blockIdx.x, tid = threadIdx.x;
    const int lane = tid & 63, wid = tid >> 6;

    __shared__ float4 sbox[NBOX];          // 32 KiB
    __shared__ float  sscore[NBOX];        //  8 KiB
    __shared__ ull    skeys[NBOX];         // 16 KiB
    __shared__ ull    sdead[2][8];
    __shared__ float4 skept[MAX_INST];
    __shared__ float  skeptsc[MAX_INST];
    __shared__ int    s_m;

    const size_t bb = (size_t)b * NBOX;
    for (int i = tid; i < NBOX; i += NBLOCK) {
        sbox[i]   = wsbox[bb + i];
        skeys[i]  = wskeys[bb + i];
        sscore[i] = scores_in[bb + i];
    }
    __syncthreads();

    const int h  = wid & 1;   // which 64-half of the 128-window
    const int st = wid >> 1;  // kept-stride slot (0..7)

    // Preload window 0 candidates.
    int oi0 = (int)(skeys[h * 64 + lane] & 0xFFFFFFFFull);
    float4 bx = sbox[oi0];
    float  sc = sscore[oi0];
    float4 bxB; float scB;             // wave 0 only: half-1 candidate
    if (wid == 0) {
        int oiB = (int)(skeys[64 + lane] & 0xFFFFFFFFull);
        bxB = sbox[oiB]; scB = sscore[oiB];
    }

    int count = 0;
    for (int base = 0; base < NBOX && count < MAX_INST; base += 128) {
        // Prefetch next window's candidates (independent of this window).
        float4 nbx = bx; float nsc = sc;
        float4 nbxB = bx; float nscB = 0.f;
        const bool havenext = (base + 128 < NBOX);
        if (havenext) {
            int noi = (int)(skeys[base + 128 + h * 64 + lane] & 0xFFFFFFFFull);
            nbx = sbox[noi]; nsc = sscore[noi];
            if (wid == 0) {
                int noiB = (int)(skeys[base + 192 + lane] & 0xFFFFFFFFull);
                nbxB = sbox[noiB]; nscB = sscore[noiB];
            }
        }

        // Dead-check current candidates vs kept list, strided over 8 slots.
        bool deadp = (sc < MIN_CONF);
        for (int k = st; k < count; k += 8)
            deadp |= (iou_pair(skept[k], bx) > NMS_THR);
        ull bal = __ballot(deadp);
        if (lane == 0) sdead[h][st] = bal;
        __syncthreads();

        // Wave 0: greedy chain over the 128-bit alive vector.
        if (wid == 0) {
            ull d0 = sdead[0][0], d1 = sdead[1][0];
#pragma unroll
            for (int q = 1; q < 8; ++q) { d0 |= sdead[0][q]; d1 |= sdead[1][q]; }
            ull a0 = ~d0, a1 = ~d1;
            int m = 0;
            const int maxm = MAX_INST - count;
            while ((a0 | a1) && m < maxm) {
                const bool inA = (a0 != 0);
                const int il = inA ? __builtin_ctzll(a0) : __builtin_ctzll(a1);
                float4 kb; float ks;
                if (inA) {
                    kb.x = __shfl(bx.x, il); kb.y = __shfl(bx.y, il);
                    kb.z = __shfl(bx.z, il); kb.w = __shfl(bx.w, il);
                    ks = __shfl(sc, il);
                } else {
                    kb.x = __shfl(bxB.x, il); kb.y = __shfl(bxB.y, il);
                    kb.z = __shfl(bxB.z, il); kb.w = __shfl(bxB.w, il);
                    ks = __shfl(scB, il);
                }
                if (lane == 0) { skept[count + m] = kb; skeptsc[count + m] = ks; }
                ++m;
                ull supA = __ballot(iou_pair(kb, bx)  > NMS_THR);
                ull supB = __ballot(iou_pair(kb, bxB) > NMS_THR);
                if (inA) supA |= (1ull << il); else supB |= (1ull << il);
                a0 &= ~supA; a1 &= ~supB;
            }
            if (lane == 0) s_m = m;
        }
        __syncthreads();
        count += s_m;

        bx = nbx; sc = nsc;
        if (wid == 0) { bxB = nbxB; scB = nscB; }
    }

    // Epilogue: write all MAX_INST rows (kept values, zeros elsewhere).
    for (int i = tid; i < MAX_INST * 5; i += NBLOCK) {
        int r = i / 5, c = i % 5;
        float vv = 0.0f;
        if (r < count) {
            float4 kb = skept[r];
            vv = (c == 0) ? kb.x
               : (c == 1) ? kb.y
               : (c == 2) ? kb.z
               : (c == 3) ? kb.w
               :            skeptsc[r];
        }
        out[(size_t)b * MAX_INST * 5 + i] = vv;
    }
}

extern "C" void kernel_launch(void* const* d_in, const int* in_sizes, int n_in,
                              void* d_out, int out_size, void* d_ws, size_t ws_size,
                              hipStream_t stream) {
    const float* rois    = (const float*)d_in[0];
    const float* scores  = (const float*)d_in[1];
    const float* deltas  = (const float*)d_in[2];
    const float* window  = (const float*)d_in[3];
    float* out = (float*)d_out;

    float4* wsbox  = (float4*)d_ws;
    ull*    wskeys = (ull*)((char*)d_ws + (size_t)NBATCH * NBOX * sizeof(float4));

    k_decode<<<NBATCH * NBOX / 256, 256, 0, stream>>>(rois, deltas, window, wsbox);
    k_sort<<<NBATCH, SBLOCK, 0, stream>>>(scores, wskeys);
    k_nms<<<NBATCH, NBLOCK, 0, stream>>>(wsbox, wskeys, scores, out);
}

// Round 9
// 56.865 us; speedup vs baseline: 1.1472x; 1.1472x over previous
//
#include <hip/hip_runtime.h>
#include <math.h>

#define NBOX 2048
#define NBATCH 8
#define MAX_INST 100
#define MIN_CONF 0.15f
#define NMS_THR 0.3f
#define BLOCK 512
#define NWIN 16        // NBOX / 128

typedef unsigned long long ull;

// Decode one box exactly in the reference's f32 op order (no FMA contraction).
__device__ inline float4 decode_box(float4 r, float4 d,
                                    float wy1, float wx1, float wy2, float wx2) {
    float h  = __fsub_rn(r.z, r.x);
    float w  = __fsub_rn(r.w, r.y);
    float dy = __fmul_rn(d.x, 0.1f);
    float dx = __fmul_rn(d.y, 0.1f);
    float dh = __fmul_rn(d.z, 0.2f);
    float dw = __fmul_rn(d.w, 0.2f);
    float cy = __fadd_rn(__fadd_rn(r.x, __fmul_rn(0.5f, h)), __fmul_rn(dy, h));
    float cx = __fadd_rn(__fadd_rn(r.y, __fmul_rn(0.5f, w)), __fmul_rn(dx, w));
    float h2 = __fmul_rn(h, expf(dh));
    float w2 = __fmul_rn(w, expf(dw));
    float y1 = __fsub_rn(cy, __fmul_rn(0.5f, h2));
    float x1 = __fsub_rn(cx, __fmul_rn(0.5f, w2));
    float y2 = __fadd_rn(y1, h2);
    float x2 = __fadd_rn(x1, w2);
    float4 b;
    b.x = fminf(fmaxf(y1, wy1), wy2);
    b.y = fminf(fmaxf(x1, wx1), wx2);
    b.z = fminf(fmaxf(y2, wy1), wy2);
    b.w = fminf(fmaxf(x2, wx1), wx2);
    return b;
}

// IoU with precomputed areas; identical f32 op order to the reference
// (areas computed with the reference's exact ops at load time).
__device__ inline float iou_pa(float ax, float ay, float az, float aw2, float areaA,
                               float4 b, float areaB) {
    float iy1 = fmaxf(ax,  b.x);
    float ix1 = fmaxf(ay,  b.y);
    float iy2 = fminf(az,  b.z);
    float ix2 = fminf(aw2, b.w);
    float ih = fmaxf(__fsub_rn(iy2, iy1), 0.0f);
    float iw = fmaxf(__fsub_rn(ix2, ix1), 0.0f);
    float inter = __fmul_rn(ih, iw);
    float uni = __fadd_rn(__fsub_rn(__fadd_rn(areaA, areaB), inter), 1e-8f);
    return __fdiv_rn(inter, uni);
}

__device__ inline ull shfl_xor64(ull x, int d) {
    unsigned lo = (unsigned)x, hi = (unsigned)(x >> 32);
    lo = __shfl_xor(lo, d);
    hi = __shfl_xor(hi, d);
    return ((ull)hi << 32) | lo;
}

__device__ inline void cmpsel(ull& a, ull& b, bool takeMinA) {
    ull mn = a < b ? a : b;
    ull mx = a < b ? b : a;
    a = takeMinA ? mn : mx;
    b = takeMinA ? mx : mn;
}

__device__ inline float readlane_f(float x, int sl) {
    return __uint_as_float((unsigned)__builtin_amdgcn_readlane((int)__float_as_uint(x), sl));
}

__global__ __launch_bounds__(BLOCK)
void detect_refine_kernel(const float* __restrict__ rois,
                          const float* __restrict__ scores_in,
                          const float* __restrict__ deltas,
                          const float* __restrict__ window,
                          float* __restrict__ out) {
    const int b    = blockIdx.x;
    const int tid  = threadIdx.x;
    const int lane = tid & 63;
    const int wid  = tid >> 6;

    __shared__ ull    keys[NBOX];           // 16 KiB  (~score_bits)<<32 | orig_idx
    __shared__ float4 sboxes[NBOX];         // 32 KiB  decoded boxes, ORIGINAL idx
    __shared__ float  sscores[NBOX];        //  8 KiB  ORIGINAL idx
    __shared__ ull    sdead[2][2][8];       // [parity][half][slot]
    __shared__ float4 skept[MAX_INST];
    __shared__ float  skeptsc[MAX_INST];
    __shared__ float  skeptar[MAX_INST];
    __shared__ int    s_m;

    const float wy1 = window[b * 4 + 0];
    const float wx1 = window[b * 4 + 1];
    const float wy2 = window[b * 4 + 2];
    const float wx2 = window[b * 4 + 3];

    float* outb = out + (size_t)b * MAX_INST * 5;

    // ---- Phase A1: coalesced load + decode, stored by ORIGINAL index ----
    for (int e = tid; e < NBOX; e += BLOCK) {
        float4 r = ((const float4*)rois)[b * NBOX + e];
        float4 d = ((const float4*)deltas)[b * NBOX + e];
        float  s = scores_in[b * NBOX + e];
        sboxes[e]  = decode_box(r, d, wy1, wx1, wy2, wx2);
        sscores[e] = s;
    }

    // ---- Phase A2: sort keys in registers (4 consecutive elements/thread) ----
    const int e0 = tid * 4;
    ull v[4];
    {
        float4 sc = ((const float4*)(scores_in + (size_t)b * NBOX))[tid];
        float s4[4] = {sc.x, sc.y, sc.z, sc.w};
#pragma unroll
        for (int s = 0; s < 4; ++s) {
            unsigned u = __float_as_uint(s4[s]);
            u = (u & 0x80000000u) ? ~u : (u | 0x80000000u);
            v[s] = ((ull)(~u) << 32) | (unsigned)(e0 + s);
        }
    }

    // ---- Phase B: bitonic sort ascending (= score descending, stable) ----
    for (unsigned k = 2; k <= NBOX; k <<= 1) {
        if (k >= 512) {
#pragma unroll
            for (int s = 0; s < 4; ++s) keys[e0 + s] = v[s];
            __syncthreads();
            for (unsigned j = k >> 1; j >= 256; j >>= 1) {
                for (int t = tid; t < NBOX / 2; t += BLOCK) {
                    int i = 2 * t - (t & (j - 1));
                    int p = i | j;
                    bool up = ((i & k) == 0);
                    ull a = keys[i], c = keys[p];
                    bool sw = up ? (a > c) : (a < c);
                    if (sw) { keys[i] = c; keys[p] = a; }
                }
                __syncthreads();
            }
#pragma unroll
            for (int s = 0; s < 4; ++s) v[s] = keys[e0 + s];
        }
        unsigned jstart = ((k >> 1) > 128u) ? 128u : (k >> 1);
        for (unsigned j = jstart; j >= 4; j >>= 1) {
            int d = (int)(j >> 2);
#pragma unroll
            for (int s = 0; s < 4; ++s) {
                ull p = shfl_xor64(v[s], d);
                int e = e0 + s;
                bool takeMin = (((e & j) == 0) == ((e & k) == 0));
                v[s] = takeMin ? (v[s] < p ? v[s] : p) : (v[s] > p ? v[s] : p);
            }
        }
        if (k >= 4) {   // j == 2
            bool up = ((e0 & k) == 0);
            cmpsel(v[0], v[2], up);
            cmpsel(v[1], v[3], up);
        }
        {               // j == 1
            bool upA = ((e0 & k) == 0);
            bool upB = (((e0 + 2) & k) == 0);
            cmpsel(v[0], v[1], upA);
            cmpsel(v[2], v[3], upB);
        }
    }
#pragma unroll
    for (int s = 0; s < 4; ++s) keys[e0 + s] = v[s];
    __syncthreads();

    // ---- Phase C: 128-wide windows; chain (wave 0) overlapped with
    //      next-window dead-check (waves 1-7); parity-buffered sdead. ----
#define LDCAND(W, B0, B1, S0, S1, A0, A1)                                   \
    {                                                                       \
        int base_ = (W) << 7;                                               \
        int o0_ = (int)(keys[base_ + lane]      & 0xFFFFFFFFull);           \
        int o1_ = (int)(keys[base_ + 64 + lane] & 0xFFFFFFFFull);           \
        B0 = sboxes[o0_]; B1 = sboxes[o1_];                                 \
        S0 = sscores[o0_]; S1 = sscores[o1_];                               \
        A0 = __fmul_rn(__fsub_rn(B0.z, B0.x), __fsub_rn(B0.w, B0.y));       \
        A1 = __fmul_rn(__fsub_rn(B1.z, B1.x), __fsub_rn(B1.w, B1.y));       \
    }

    float4 c0, c1, n0, n1;
    float  cs0, cs1, ns0, ns1, ca0, ca1, na0, na1;

    // Prologue: load window 0; dead-check it (count==0 -> MIN_CONF only).
    LDCAND(0, c0, c1, cs0, cs1, ca0, ca1);
    if (wid == 0) {
        if (lane < 2) sdead[0][lane][0] = 0;
    } else {
        bool d0p = (wid == 1) && (cs0 < MIN_CONF);
        bool d1p = (wid == 1) && (cs1 < MIN_CONF);
        ull b0 = __ballot(d0p), b1 = __ballot(d1p);
        if (lane == 0) { sdead[0][0][wid] = b0; sdead[0][1][wid] = b1; }
    }
    __syncthreads();

    int count = 0;
    for (int w = 0; w < NWIN; ++w) {
        const int par = w & 1, pnx = par ^ 1;
        const int cnt0 = count;

        if (wid == 0) {
            // Greedy chain over this window's 128-bit alive vector.
            ull d0 = 0, d1 = 0;
#pragma unroll
            for (int q = 0; q < 8; ++q) { d0 |= sdead[par][0][q]; d1 |= sdead[par][1][q]; }
            ull al0 = ~d0, al1 = ~d1;
            int m = 0;
            const int maxm = MAX_INST - cnt0;
            while ((al0 | al1) && m < maxm) {
                const bool inA = (al0 != 0);
                ull aw = inA ? al0 : al1;
                int il = __builtin_amdgcn_readfirstlane((int)__builtin_ctzll(aw));
                float kx = readlane_f(inA ? c0.x : c1.x, il);
                float ky = readlane_f(inA ? c0.y : c1.y, il);
                float kz = readlane_f(inA ? c0.z : c1.z, il);
                float kw = readlane_f(inA ? c0.w : c1.w, il);
                float ka = readlane_f(inA ? ca0  : ca1,  il);
                float ks = readlane_f(inA ? cs0  : cs1,  il);
                if (lane == 0) {
                    skept[cnt0 + m]   = make_float4(kx, ky, kz, kw);
                    skeptsc[cnt0 + m] = ks;
                    skeptar[cnt0 + m] = ka;
                }
                ++m;
                ull supA = __ballot(iou_pa(kx, ky, kz, kw, ka, c0, ca0) > NMS_THR);
                ull supB = __ballot(iou_pa(kx, ky, kz, kw, ka, c1, ca1) > NMS_THR);
                if (inA) supA |= (1ull << il); else supB |= (1ull << il);
                al0 &= ~supA; al1 &= ~supB;
            }
            if (lane == 0) s_m = m;
        } else if (w + 1 < NWIN) {
            // Pre-dead-check window w+1 vs kept[0..cnt0), strided over 7 waves.
            LDCAND(w + 1, n0, n1, ns0, ns1, na0, na1);
            bool d0p = (wid == 1) && (ns0 < MIN_CONF);
            bool d1p = (wid == 1) && (ns1 < MIN_CONF);
            for (int k = wid - 1; k < cnt0; k += 7) {
                float4 kb = skept[k]; float ka = skeptar[k];
                d0p |= (iou_pa(kb.x, kb.y, kb.z, kb.w, ka, n0, na0) > NMS_THR);
                d1p |= (iou_pa(kb.x, kb.y, kb.z, kb.w, ka, n1, na1) > NMS_THR);
            }
            ull b0 = __ballot(d0p), b1 = __ballot(d1p);
            if (lane == 0) { sdead[pnx][0][wid] = b0; sdead[pnx][1][wid] = b1; }
        }
        __syncthreads();

        count += s_m;
        if (count >= MAX_INST || w + 1 >= NWIN) break;

        // Incremental dead-check of w+1 vs keeps added this window.
        if (wid == 0) LDCAND(w + 1, n0, n1, ns0, ns1, na0, na1);
        {
            bool d0i = false, d1i = false;
            for (int k = cnt0 + wid; k < count; k += 8) {
                float4 kb = skept[k]; float ka = skeptar[k];
                d0i |= (iou_pa(kb.x, kb.y, kb.z, kb.w, ka, n0, na0) > NMS_THR);
                d1i |= (iou_pa(kb.x, kb.y, kb.z, kb.w, ka, n1, na1) > NMS_THR);
            }
            ull b0 = __ballot(d0i), b1 = __ballot(d1i);
            if (lane == 0) {
                if (wid == 0) { sdead[pnx][0][0] = b0;  sdead[pnx][1][0] = b1; }
                else          { sdead[pnx][0][wid] |= b0; sdead[pnx][1][wid] |= b1; }
            }
        }
        __syncthreads();

        c0 = n0; c1 = n1; cs0 = ns0; cs1 = ns1; ca0 = na0; ca1 = na1;
    }
#undef LDCAND

    // ---- Epilogue: write all MAX_INST rows (kept values, zeros elsewhere) ----
    for (int i = tid; i < MAX_INST * 5; i += BLOCK) {
        int r = i / 5, c = i % 5;
        float vv = 0.0f;
        if (r < count) {
            float4 kb = skept[r];
            vv = (c == 0) ? kb.x
               : (c == 1) ? kb.y
               : (c == 2) ? kb.z
               : (c == 3) ? kb.w
               :            skeptsc[r];
        }
        outb[i] = vv;
    }
}

extern "C" void kernel_launch(void* const* d_in, const int* in_sizes, int n_in,
                              void* d_out, int out_size, void* d_ws, size_t ws_size,
                              hipStream_t stream) {
    const float* rois    = (const float*)d_in[0];
    const float* scores  = (const float*)d_in[1];
    const float* deltas  = (const float*)d_in[2];
    const float* window  = (const float*)d_in[3];
    float* out = (float*)d_out;
    detect_refine_kernel<<<NBATCH, BLOCK, 0, stream>>>(rois, scores, deltas, window, out);
}

// Round 10
// 49.441 us; speedup vs baseline: 1.3194x; 1.1502x over previous
//
#include <hip/hip_runtime.h>
#include <math.h>

#define NBOX 2048
#define NBATCH 8
#define MAX_INST 100
#define MIN_CONF 0.15f
#define NMS_THR 0.3f
#define BLOCK 512
#define NWAVE 8

typedef unsigned long long ull;

// Decode one box exactly in the reference's f32 op order (no FMA contraction).
__device__ inline float4 decode_box(float4 r, float4 d,
                                    float wy1, float wx1, float wy2, float wx2) {
    float h  = __fsub_rn(r.z, r.x);
    float w  = __fsub_rn(r.w, r.y);
    float dy = __fmul_rn(d.x, 0.1f);
    float dx = __fmul_rn(d.y, 0.1f);
    float dh = __fmul_rn(d.z, 0.2f);
    float dw = __fmul_rn(d.w, 0.2f);
    float cy = __fadd_rn(__fadd_rn(r.x, __fmul_rn(0.5f, h)), __fmul_rn(dy, h));
    float cx = __fadd_rn(__fadd_rn(r.y, __fmul_rn(0.5f, w)), __fmul_rn(dx, w));
    float h2 = __fmul_rn(h, expf(dh));
    float w2 = __fmul_rn(w, expf(dw));
    float y1 = __fsub_rn(cy, __fmul_rn(0.5f, h2));
    float x1 = __fsub_rn(cx, __fmul_rn(0.5f, w2));
    float y2 = __fadd_rn(y1, h2);
    float x2 = __fadd_rn(x1, w2);
    float4 b;
    b.x = fminf(fmaxf(y1, wy1), wy2);
    b.y = fminf(fmaxf(x1, wx1), wx2);
    b.z = fminf(fmaxf(y2, wy1), wy2);
    b.w = fminf(fmaxf(x2, wx1), wx2);
    return b;
}

// IoU with precomputed areas; identical f32 op order to the reference.
__device__ inline float iou_pa(float ax, float ay, float az, float aw2, float areaA,
                               float4 b, float areaB) {
    float iy1 = fmaxf(ax,  b.x);
    float ix1 = fmaxf(ay,  b.y);
    float iy2 = fminf(az,  b.z);
    float ix2 = fminf(aw2, b.w);
    float ih = fmaxf(__fsub_rn(iy2, iy1), 0.0f);
    float iw = fmaxf(__fsub_rn(ix2, ix1), 0.0f);
    float inter = __fmul_rn(ih, iw);
    float uni = __fadd_rn(__fsub_rn(__fadd_rn(areaA, areaB), inter), 1e-8f);
    return __fdiv_rn(inter, uni);
}

__device__ inline ull shfl_xor64(ull x, int d) {
    unsigned lo = (unsigned)x, hi = (unsigned)(x >> 32);
    lo = __shfl_xor(lo, d);
    hi = __shfl_xor(hi, d);
    return ((ull)hi << 32) | lo;
}

__device__ inline void cmpsel(ull& a, ull& b, bool takeMinA) {
    ull mn = a < b ? a : b;
    ull mx = a < b ? b : a;
    a = takeMinA ? mn : mx;
    b = takeMinA ? mx : mn;
}

__device__ inline float readlane_f(float x, int sl) {
    return __uint_as_float((unsigned)__builtin_amdgcn_readlane((int)__float_as_uint(x), sl));
}

__global__ __launch_bounds__(BLOCK)
void detect_refine_kernel(const float* __restrict__ rois,
                          const float* __restrict__ scores_in,
                          const float* __restrict__ deltas,
                          const float* __restrict__ window,
                          float* __restrict__ out) {
    const int b    = blockIdx.x;
    const int tid  = threadIdx.x;
    const int lane = tid & 63;
    const int wid  = tid >> 6;

    __shared__ ull    keys[NBOX];          // 16 KiB  (~score_bits)<<32 | orig_idx
    __shared__ float4 sbox[NBOX];          // 32 KiB  decoded boxes, SORTED rank
    __shared__ float  sarea[NBOX];         //  8 KiB  SORTED rank
    __shared__ float  sscore[NBOX];        //  8 KiB  SORTED rank
    __shared__ ull    dead8[NWAVE];
    __shared__ float4 skept[MAX_INST];
    __shared__ float  skeptar[MAX_INST];
    __shared__ float  skeptsc[MAX_INST];
    __shared__ int    s_m;

    const float wy1 = window[b * 4 + 0];
    const float wx1 = window[b * 4 + 1];
    const float wy2 = window[b * 4 + 2];
    const float wx2 = window[b * 4 + 3];

    float* outb = out + (size_t)b * MAX_INST * 5;

    // ---- Phase A: sort keys in registers (4 consecutive elements/thread) ----
    const int e0 = tid * 4;
    ull v[4];
    {
        float4 sc = ((const float4*)(scores_in + (size_t)b * NBOX))[tid];
        float s4[4] = {sc.x, sc.y, sc.z, sc.w};
#pragma unroll
        for (int s = 0; s < 4; ++s) {
            unsigned u = __float_as_uint(s4[s]);
            u = (u & 0x80000000u) ? ~u : (u | 0x80000000u);
            v[s] = ((ull)(~u) << 32) | (unsigned)(e0 + s);
        }
    }
    for (unsigned k = 2; k <= NBOX; k <<= 1) {
        if (k >= 512) {
#pragma unroll
            for (int s = 0; s < 4; ++s) keys[e0 + s] = v[s];
            __syncthreads();
            for (unsigned j = k >> 1; j >= 256; j >>= 1) {
                for (int t = tid; t < NBOX / 2; t += BLOCK) {
                    int i = 2 * t - (t & (j - 1));
                    int p = i | j;
                    bool up = ((i & k) == 0);
                    ull a = keys[i], c = keys[p];
                    bool sw = up ? (a > c) : (a < c);
                    if (sw) { keys[i] = c; keys[p] = a; }
                }
                __syncthreads();
            }
#pragma unroll
            for (int s = 0; s < 4; ++s) v[s] = keys[e0 + s];
        }
        unsigned jstart = ((k >> 1) > 128u) ? 128u : (k >> 1);
        for (unsigned j = jstart; j >= 4; j >>= 1) {
            int d = (int)(j >> 2);
#pragma unroll
            for (int s = 0; s < 4; ++s) {
                ull p = shfl_xor64(v[s], d);
                int e = e0 + s;
                bool takeMin = (((e & j) == 0) == ((e & k) == 0));
                v[s] = takeMin ? (v[s] < p ? v[s] : p) : (v[s] > p ? v[s] : p);
            }
        }
        if (k >= 4) {   // j == 2
            bool up = ((e0 & k) == 0);
            cmpsel(v[0], v[2], up);
            cmpsel(v[1], v[3], up);
        }
        {               // j == 1
            bool upA = ((e0 & k) == 0);
            bool upB = (((e0 + 2) & k) == 0);
            cmpsel(v[0], v[1], upA);
            cmpsel(v[2], v[3], upB);
        }
    }

    // ---- Phase P: permute+decode directly into SORTED-rank arrays ----
    // (this thread owns ranks e0..e0+3; gather inputs from global by orig idx)
#pragma unroll
    for (int s = 0; s < 4; ++s) {
        int r = e0 + s;
        int oi = (int)(v[s] & 0xFFFFFFFFull);
        float4 rr = ((const float4*)rois)[b * NBOX + oi];
        float4 dd = ((const float4*)deltas)[b * NBOX + oi];
        float4 bb = decode_box(rr, dd, wy1, wx1, wy2, wx2);
        sbox[r]   = bb;
        sarea[r]  = __fmul_rn(__fsub_rn(bb.z, bb.x), __fsub_rn(bb.w, bb.y));
        sscore[r] = scores_in[b * NBOX + oi];
    }
    __syncthreads();

    // ---- Phase C: 64-wide windows; parallel dead-check + wave-0 chain ----
    int count = 0;
    for (int base = 0; base < NBOX && count < MAX_INST; base += 64) {
        // Candidate for this lane (direct, contiguous, no indirection).
        float4 cb = sbox[base + lane];
        float  ca = sarea[base + lane];
        float  cs = sscore[base + lane];

        // Dead-check vs kept list, strided over waves, 2-way unrolled loads.
        bool deadp = (cs < MIN_CONF);
        {
            int k = wid;
            for (; k + 8 < count; k += 16) {
                float4 k1 = skept[k];     float a1 = skeptar[k];
                float4 k2 = skept[k + 8]; float a2 = skeptar[k + 8];
                deadp |= (iou_pa(k1.x, k1.y, k1.z, k1.w, a1, cb, ca) > NMS_THR);
                deadp |= (iou_pa(k2.x, k2.y, k2.z, k2.w, a2, cb, ca) > NMS_THR);
            }
            if (k < count) {
                float4 k1 = skept[k]; float a1 = skeptar[k];
                deadp |= (iou_pa(k1.x, k1.y, k1.z, k1.w, a1, cb, ca) > NMS_THR);
            }
        }
        ull bal = __ballot(deadp);
        if (lane == 0) dead8[wid] = bal;
        __syncthreads();

        // Wave 0: maskless greedy chain, readlane broadcasts.
        if (wid == 0) {
            ull dead = dead8[0];
#pragma unroll
            for (int q = 1; q < NWAVE; ++q) dead |= dead8[q];
            ull alive = ~dead;
            int m = 0;
            const int maxm = MAX_INST - count;
            while (alive && m < maxm) {
                int il = __builtin_amdgcn_readfirstlane((int)__builtin_ctzll(alive));
                float kx = readlane_f(cb.x, il);
                float ky = readlane_f(cb.y, il);
                float kz = readlane_f(cb.z, il);
                float kw = readlane_f(cb.w, il);
                float ka = readlane_f(ca,   il);
                float ks = readlane_f(cs,   il);
                if (lane == 0) {
                    skept[count + m]   = make_float4(kx, ky, kz, kw);
                    skeptar[count + m] = ka;
                    skeptsc[count + m] = ks;
                }
                ++m;
                ull sup = __ballot(iou_pa(kx, ky, kz, kw, ka, cb, ca) > NMS_THR);
                alive &= ~sup;
                alive &= ~(1ull << il);
            }
            if (lane == 0) s_m = m;
        }
        __syncthreads();
        count += s_m;
    }

    // ---- Epilogue: write all MAX_INST rows (kept values, zeros elsewhere) ----
    for (int i = tid; i < MAX_INST * 5; i += BLOCK) {
        int r = i / 5, c = i % 5;
        float vv = 0.0f;
        if (r < count) {
            float4 kb = skept[r];
            vv = (c == 0) ? kb.x
               : (c == 1) ? kb.y
               : (c == 2) ? kb.z
               : (c == 3) ? kb.w
               :            skeptsc[r];
        }
        outb[i] = vv;
    }
}

extern "C" void kernel_launch(void* const* d_in, const int* in_sizes, int n_in,
                              void* d_out, int out_size, void* d_ws, size_t ws_size,
                              hipStream_t stream) {
    const float* rois    = (const float*)d_in[0];
    const float* scores  = (const float*)d_in[1];
    const float* deltas  = (const float*)d_in[2];
    const float* window  = (const float*)d_in[3];
    float* out = (float*)d_out;
    detect_refine_kernel<<<NBATCH, BLOCK, 0, stream>>>(rois, scores, deltas, window, out);
}